// Round 2
// baseline (259.718 us; speedup 1.0000x reference)
//
#include <hip/hip_runtime.h>

#define BB  4
#define CC  64
#define HH  128
#define WW  128
#define KS  21
#define PAD 10
#define CH  4            // channels staged per LDS chunk
#define LROW 160         // LDS row stride in floats: 16 zero | 128 data | 16 zero

// Block: 256 threads = 8 rows x 32 pixel-quads, one di per block.
// f2 rows staged in LDS (zero-padded left/right, OOB rows zeroed) so the
// compute loop has no conditionals and window reads come from LDS, not L1.
__global__ __launch_bounds__(256, 3) void corr_kernel(
    const float* __restrict__ feat1,
    const float* __restrict__ feat2,
    float* __restrict__ out)
{
    __shared__ float lds[CH * 8 * LROW];   // [c_local][row][LROW] = 20 KB

    const int tid = threadIdx.x;
    int bi = blockIdx.x;
    const int di = bi % KS;  bi /= KS;
    const int h8 = bi % (HH / 8);
    const int b  = bi / (HH / 8);

    // Zero the pad columns once. Staging only ever writes cols [16,144).
    {
        const int rr = tid >> 3;           // 0..31 = c_local*8 + row
        const int q  = tid & 7;            // 8 float4s of pad per row
        const int col = (q < 4) ? (q << 2) : (144 + ((q - 4) << 2));
        *(float4*)&lds[rr * LROW + col] = make_float4(0.f, 0.f, 0.f, 0.f);
    }

    const int h  = h8 * 8 + (tid >> 5);
    const int w0 = (tid & 31) << 2;
    const int r0 = h8 * 8 + di - PAD;      // f2 row for local row 0

    // staging assignment: thread -> (row, quad)
    const int s_q   = tid & 31;
    const int s_row = (tid >> 5) & 7;
    const int sr    = r0 + s_row;
    const bool s_ok = (sr >= 0) && (sr < HH);
    const float* f2p = feat2 + ((size_t)(b * CC) * HH + (s_ok ? sr : 0)) * WW + (s_q << 2);
    float* ldst = &lds[s_row * LROW + 16 + (s_q << 2)];

    const float* f1p = feat1 + ((size_t)(b * CC) * HH + h) * WW + w0;

    float acc[4][KS];
#pragma unroll
    for (int p = 0; p < 4; ++p)
#pragma unroll
        for (int d = 0; d < KS; ++d) acc[p][d] = 0.0f;

    for (int c0 = 0; c0 < CC; c0 += CH) {
        __syncthreads();
#pragma unroll
        for (int cl = 0; cl < CH; ++cl) {
            float4 v = make_float4(0.f, 0.f, 0.f, 0.f);
            if (s_ok)
                v = *(const float4*)(f2p + (size_t)(c0 + cl) * (HH * WW));
            *(float4*)(ldst + cl * (8 * LROW)) = v;
        }
        __syncthreads();

#pragma unroll
        for (int cl = 0; cl < CH; ++cl) {
            const float4 a = *(const float4*)(f1p + (size_t)(c0 + cl) * (HH * WW));
            // window base: lds col (16 + w0 - 12) = w0 + 4 (16B aligned)
            const float* wp = &lds[(cl * 8 + (tid >> 5)) * LROW + 4 + w0];
            float win[28];
#pragma unroll
            for (int j = 0; j < 7; ++j) {
                const float4 t = *(const float4*)(wp + (j << 2));
                win[4 * j + 0] = t.x;
                win[4 * j + 1] = t.y;
                win[4 * j + 2] = t.z;
                win[4 * j + 3] = t.w;
            }
            // f2 col for (p,d) = w0+p+d-10 -> win[p+d+2]
#pragma unroll
            for (int d = 0; d < KS; ++d) {
                acc[0][d] += a.x * win[d + 2];
                acc[1][d] += a.y * win[d + 3];
                acc[2][d] += a.z * win[d + 4];
                acc[3][d] += a.w * win[d + 5];
            }
        }
    }

    const float scale = 1.0f / (float)CC;
    float* op = out + (((size_t)b * (KS * KS) + (size_t)di * KS) * HH + h) * WW + w0;
#pragma unroll
    for (int d = 0; d < KS; ++d) {
        float4 v = make_float4(acc[0][d] * scale, acc[1][d] * scale,
                               acc[2][d] * scale, acc[3][d] * scale);
        *(float4*)(op + (size_t)d * (HH * WW)) = v;
    }
}

extern "C" void kernel_launch(void* const* d_in, const int* in_sizes, int n_in,
                              void* d_out, int out_size, void* d_ws, size_t ws_size,
                              hipStream_t stream) {
    const float* feat1 = (const float*)d_in[0];
    const float* feat2 = (const float*)d_in[1];
    float* out = (float*)d_out;

    const int blocks = BB * (HH / 8) * KS;   // 1344
    corr_kernel<<<blocks, 256, 0, stream>>>(feat1, feat2, out);
}